// Round 1
// baseline (277.134 us; speedup 1.0000x reference)
//
#include <hip/hip_runtime.h>

// loss = a*sum(pn^2) + 2*sum(z)*sum(pn) + sum(z^2)*(N - a)
//   z = (margin - p) on positives, pn = p on negatives, a = #positives.
// Streaming reduction: 268 MB read, one scalar out. Roofline ~43 us @ 6.3 TB/s.
//
// R5 theory: prior structure gave each wave ONE 16-load batch then died ->
// bursty memory pipeline (zero loads in flight during reduce/drain/redispatch)
// + 4096 block dispatches + per-block epilogue. This version: 1024 persistent
// blocks, grid-stride over tiles, ping-pong register double-buffer so every
// wave keeps 16 loads (16 KiB) in flight while consuming the previous batch.
// Named A/B buffers (no runtime-indexed register arrays -> no scratch).
// sched_barrier(0) after each load batch: scheduler may not sink loads into
// the consume (R4 lesson: it otherwise re-interleaves to minimize liveness).

constexpr float MARGIN = 1.0f;

#define BANK_STRIDE 32            // floats; 128 B = one L2 line per bank
#define BLOCK 256
#define GPT 8                     // float4-groups per thread per tile
#define GROUPS_PER_TILE (BLOCK * GPT)   // 2048 float4-groups = 8192 elements
#define PERSISTENT_BLOCKS 1024

struct Acc { float a, sz, sz2, sp, sp2; };

__device__ __forceinline__ float wave_reduce(float v) {
    #pragma unroll
    for (int off = 32; off > 0; off >>= 1) v += __shfl_down(v, off, 64);
    return v;
}

__device__ __forceinline__ void acc1(float px, int lx, Acc& s) {
    float ispos = (lx == 1) ? 1.0f : 0.0f;
    float z  = ispos * (MARGIN - px);
    s.a   += ispos;
    s.sz  += z;
    s.sz2  = fmaf(z, z, s.sz2);
    float pn = (lx == 1) ? 0.0f : px;
    s.sp  += pn;
    s.sp2  = fmaf(pn, pn, s.sp2);
}

__device__ __forceinline__ void load_batch(
    const float4* __restrict__ p4, const int4* __restrict__ l4,
    int tile, int tid, float4 (&pv)[GPT], int4 (&lv)[GPT])
{
    const int b = tile * GROUPS_PER_TILE + tid;
    #pragma unroll
    for (int k = 0; k < GPT; ++k) pv[k] = p4[b + k * BLOCK];
    #pragma unroll
    for (int k = 0; k < GPT; ++k) lv[k] = l4[b + k * BLOCK];
}

__device__ __forceinline__ void consume(
    const float4 (&pv)[GPT], const int4 (&lv)[GPT], Acc& s)
{
    #pragma unroll
    for (int k = 0; k < GPT; ++k) {
        acc1(pv[k].x, lv[k].x, s);
        acc1(pv[k].y, lv[k].y, s);
        acc1(pv[k].z, lv[k].z, s);
        acc1(pv[k].w, lv[k].w, s);
    }
}

__global__ __launch_bounds__(BLOCK, 2) void hinge2_reduce(
    const float* __restrict__ pred, const int* __restrict__ lab,
    float* __restrict__ ws, int nvec, int nfull, int nbanks, int bank_stride)
{
    const float4* p4 = reinterpret_cast<const float4*>(pred);
    const int4*   l4 = reinterpret_cast<const int4*>(lab);

    Acc s = {0.f, 0.f, 0.f, 0.f, 0.f};
    const int tid    = threadIdx.x;
    const int stride = gridDim.x;

    float4 pvA[GPT], pvB[GPT];
    int4   lvA[GPT], lvB[GPT];

    // ---- persistent ping-pong pipeline over full tiles ----
    int t = blockIdx.x;
    if (t < nfull) {
        load_batch(p4, l4, t, tid, pvA, lvA);
        __builtin_amdgcn_sched_barrier(0);
        int tn = t + stride;
        while (tn < nfull) {
            load_batch(p4, l4, tn, tid, pvB, lvB);   // next tile in flight
            __builtin_amdgcn_sched_barrier(0);
            consume(pvA, lvA, s);                    // overlap with B's loads
            tn += stride;
            if (tn >= nfull) { consume(pvB, lvB, s); goto tiles_done; }
            load_batch(p4, l4, tn, tid, pvA, lvA);
            __builtin_amdgcn_sched_barrier(0);
            consume(pvB, lvB, s);
            tn += stride;
        }
        consume(pvA, lvA, s);
tiles_done: ;
    }

    // ---- remainder float4-groups (none at N=2^25, kept for generality) ----
    for (int i = nfull * GROUPS_PER_TILE + blockIdx.x * BLOCK + tid;
         i < nvec; i += stride * BLOCK) {
        float4 p = p4[i];
        int4   l = l4[i];
        acc1(p.x, l.x, s); acc1(p.y, l.y, s);
        acc1(p.z, l.z, s); acc1(p.w, l.w, s);
    }

    // ---- block reduction (once per persistent block now) ----
    s.a   = wave_reduce(s.a);
    s.sz  = wave_reduce(s.sz);
    s.sz2 = wave_reduce(s.sz2);
    s.sp  = wave_reduce(s.sp);
    s.sp2 = wave_reduce(s.sp2);

    __shared__ float sdata[4][5];
    int lane = tid & 63;
    int wid  = tid >> 6;
    if (lane == 0) {
        sdata[wid][0] = s.a;
        sdata[wid][1] = s.sz;
        sdata[wid][2] = s.sz2;
        sdata[wid][3] = s.sp;
        sdata[wid][4] = s.sp2;
    }
    __syncthreads();

    if (tid == 0) {
        float t0 = 0.f, t1 = 0.f, t2 = 0.f, t3 = 0.f, t4 = 0.f;
        #pragma unroll
        for (int w = 0; w < 4; ++w) {
            t0 += sdata[w][0];
            t1 += sdata[w][1];
            t2 += sdata[w][2];
            t3 += sdata[w][3];
            t4 += sdata[w][4];
        }
        float* bank = ws + (blockIdx.x & (nbanks - 1)) * bank_stride;
        atomicAdd(&bank[0], t0);
        atomicAdd(&bank[1], t1);
        atomicAdd(&bank[2], t2);
        atomicAdd(&bank[3], t3);
        atomicAdd(&bank[4], t4);
    }
}

__global__ __launch_bounds__(256) void hinge2_final(
    const float* __restrict__ ws,
    const float* __restrict__ pred, const int* __restrict__ lab,
    float* __restrict__ out, int n, int tail_start,
    int nbanks, int bank_stride)
{
    int t = threadIdx.x;
    float a = 0.f, sz = 0.f, sz2 = 0.f, sp = 0.f, sp2 = 0.f;
    for (int b = t; b < nbanks; b += 256) {
        const float* bank = ws + b * bank_stride;
        a   += bank[0];
        sz  += bank[1];
        sz2 += bank[2];
        sp  += bank[3];
        sp2 += bank[4];
    }
    a   = wave_reduce(a);
    sz  = wave_reduce(sz);
    sz2 = wave_reduce(sz2);
    sp  = wave_reduce(sp);
    sp2 = wave_reduce(sp2);

    __shared__ float sdata[4][5];
    int lane = t & 63, wid = t >> 6;
    if (lane == 0) {
        sdata[wid][0] = a;  sdata[wid][1] = sz; sdata[wid][2] = sz2;
        sdata[wid][3] = sp; sdata[wid][4] = sp2;
    }
    __syncthreads();

    if (t == 0) {
        double A = 0, SZ = 0, SZ2 = 0, SP = 0, SP2 = 0;
        #pragma unroll
        for (int w = 0; w < 4; ++w) {
            A   += sdata[w][0];
            SZ  += sdata[w][1];
            SZ2 += sdata[w][2];
            SP  += sdata[w][3];
            SP2 += sdata[w][4];
        }
        for (int i = tail_start; i < n; ++i) {
            float p = pred[i];
            if (lab[i] == 1) {
                double z = (double)MARGIN - (double)p;
                A += 1.0; SZ += z; SZ2 += z * z;
            } else {
                SP += (double)p; SP2 += (double)p * (double)p;
            }
        }
        double loss = A * SP2 + 2.0 * SZ * SP + SZ2 * ((double)n - A);
        out[0] = (float)loss;
    }
}

extern "C" void kernel_launch(void* const* d_in, const int* in_sizes, int n_in,
                              void* d_out, int out_size, void* d_ws, size_t ws_size,
                              hipStream_t stream)
{
    const float* pred = (const float*)d_in[0];
    const int*   lab  = (const int*)d_in[1];
    float*       out  = (float*)d_out;
    float*       ws   = (float*)d_ws;

    int n    = in_sizes[0];
    int nvec = n >> 2;                        // float4 / int4 groups
    int tail = nvec << 2;
    int nfull = nvec / GROUPS_PER_TILE;       // full tiles (4096 at N=2^25)

    int bank_stride = BANK_STRIDE;
    size_t max_banks = ws_size / (bank_stride * sizeof(float));
    int nbanks = 1;
    if (max_banks == 0) { bank_stride = 5; nbanks = 1; }
    else { while (nbanks * 2 <= (int)max_banks && nbanks < 256) nbanks <<= 1; }

    // ws is re-poisoned to 0xAA before every timed launch — zero the banks
    hipMemsetAsync(ws, 0, (size_t)nbanks * bank_stride * sizeof(float), stream);

    int blocks = nfull < PERSISTENT_BLOCKS ? nfull : PERSISTENT_BLOCKS;
    if (blocks < 1) blocks = 1;
    hinge2_reduce<<<blocks, BLOCK, 0, stream>>>(pred, lab, ws, nvec, nfull,
                                                nbanks, bank_stride);
    hinge2_final<<<1, BLOCK, 0, stream>>>(ws, pred, lab, out, n, tail,
                                          nbanks, bank_stride);
}

// Round 2
// 276.470 us; speedup vs baseline: 1.0024x; 1.0024x over previous
//
#include <hip/hip_runtime.h>

// loss = a*sum(pn^2) + 2*sum(z)*sum(pn) + sum(z^2)*(N - a)
//   z = (margin - p) on positives, pn = p on negatives, a = #positives.
// Streaming reduction: 268 MB read, one scalar out.
//
// R6 theory: R5's deep-batch + sched_barrier structure was latency-bound:
// VGPR=116 -> 4 waves/SIMD, OccupancyPercent 16%, VALUBusy 8.7%, effective
// 2.7 TB/s. The 6.3 TB/s kernels (m13 copy, m146 rmsnorm) are TLP-max:
// low VGPR, 8 waves/SIMD, simple grid-stride, no batching. This version:
//   - __launch_bounds__(256, 8): force VGPR <= 64 -> 32 waves/CU
//   - 2048 fully-resident blocks, grid-stride, 2x float4 unroll only
//   - no sched_barrier (common-mistake #5: over-engineered pipelining)
//   - per-block private ws slot, plain stores -> no atomics, no memset node

constexpr float MARGIN = 1.0f;

#define BLOCK 256
#define MAX_BLOCKS 2048
#define SLOT_STRIDE 8            // floats per block slot (32 B)

__device__ __forceinline__ float wave_reduce(float v) {
    #pragma unroll
    for (int off = 32; off > 0; off >>= 1) v += __shfl_down(v, off, 64);
    return v;
}

struct Acc { float a, sz, sz2, sp, sp2; };

__device__ __forceinline__ void acc1(float px, int lx, Acc& s) {
    float ispos = (lx == 1) ? 1.0f : 0.0f;
    float z  = ispos * (MARGIN - px);
    s.a   += ispos;
    s.sz  += z;
    s.sz2  = fmaf(z, z, s.sz2);
    float pn = (lx == 1) ? 0.0f : px;
    s.sp  += pn;
    s.sp2  = fmaf(pn, pn, s.sp2);
}

__device__ __forceinline__ void acc4(const float4& p, const int4& l, Acc& s) {
    acc1(p.x, l.x, s);
    acc1(p.y, l.y, s);
    acc1(p.z, l.z, s);
    acc1(p.w, l.w, s);
}

__global__ __launch_bounds__(BLOCK, 8) void hinge2_reduce(
    const float* __restrict__ pred, const int* __restrict__ lab,
    float* __restrict__ ws, int nvec)
{
    const float4* p4 = reinterpret_cast<const float4*>(pred);
    const int4*   l4 = reinterpret_cast<const int4*>(lab);

    Acc s = {0.f, 0.f, 0.f, 0.f, 0.f};
    const int tid  = threadIdx.x;
    const int step = gridDim.x * (BLOCK * 2);
    int i = blockIdx.x * (BLOCK * 2) + tid;

    // main grid-stride loop: 2 float4-groups per thread per iteration
    while (i + BLOCK < nvec) {
        float4 p0 = p4[i];
        float4 p1 = p4[i + BLOCK];
        int4   l0 = l4[i];
        int4   l1 = l4[i + BLOCK];
        acc4(p0, l0, s);
        acc4(p1, l1, s);
        i += step;
    }
    if (i < nvec) {                       // odd trailing group
        float4 p = p4[i];
        int4   l = l4[i];
        acc4(p, l, s);
    }

    // block reduction
    s.a   = wave_reduce(s.a);
    s.sz  = wave_reduce(s.sz);
    s.sz2 = wave_reduce(s.sz2);
    s.sp  = wave_reduce(s.sp);
    s.sp2 = wave_reduce(s.sp2);

    __shared__ float sdata[4][5];
    int lane = tid & 63;
    int wid  = tid >> 6;
    if (lane == 0) {
        sdata[wid][0] = s.a;
        sdata[wid][1] = s.sz;
        sdata[wid][2] = s.sz2;
        sdata[wid][3] = s.sp;
        sdata[wid][4] = s.sp2;
    }
    __syncthreads();

    if (tid == 0) {
        float t0 = 0.f, t1 = 0.f, t2 = 0.f, t3 = 0.f, t4 = 0.f;
        #pragma unroll
        for (int w = 0; w < 4; ++w) {
            t0 += sdata[w][0];
            t1 += sdata[w][1];
            t2 += sdata[w][2];
            t3 += sdata[w][3];
            t4 += sdata[w][4];
        }
        float* slot = ws + (size_t)blockIdx.x * SLOT_STRIDE;
        slot[0] = t0;  // plain stores to a private slot: no init required
        slot[1] = t1;
        slot[2] = t2;
        slot[3] = t3;
        slot[4] = t4;
    }
}

__global__ __launch_bounds__(BLOCK) void hinge2_final(
    const float* __restrict__ ws,
    const float* __restrict__ pred, const int* __restrict__ lab,
    float* __restrict__ out, int n, int tail_start, int nslots)
{
    int t = threadIdx.x;
    double a = 0., sz = 0., sz2 = 0., sp = 0., sp2 = 0.;
    for (int b = t; b < nslots; b += BLOCK) {
        const float* slot = ws + (size_t)b * SLOT_STRIDE;
        a   += (double)slot[0];
        sz  += (double)slot[1];
        sz2 += (double)slot[2];
        sp  += (double)slot[3];
        sp2 += (double)slot[4];
    }
    #pragma unroll
    for (int off = 32; off > 0; off >>= 1) {
        a   += __shfl_down(a,   off, 64);
        sz  += __shfl_down(sz,  off, 64);
        sz2 += __shfl_down(sz2, off, 64);
        sp  += __shfl_down(sp,  off, 64);
        sp2 += __shfl_down(sp2, off, 64);
    }

    __shared__ double sdata[4][5];
    int lane = t & 63, wid = t >> 6;
    if (lane == 0) {
        sdata[wid][0] = a;  sdata[wid][1] = sz; sdata[wid][2] = sz2;
        sdata[wid][3] = sp; sdata[wid][4] = sp2;
    }
    __syncthreads();

    if (t == 0) {
        double A = 0, SZ = 0, SZ2 = 0, SP = 0, SP2 = 0;
        #pragma unroll
        for (int w = 0; w < 4; ++w) {
            A   += sdata[w][0];
            SZ  += sdata[w][1];
            SZ2 += sdata[w][2];
            SP  += sdata[w][3];
            SP2 += sdata[w][4];
        }
        for (int i = tail_start; i < n; ++i) {
            float p = pred[i];
            if (lab[i] == 1) {
                double z = (double)MARGIN - (double)p;
                A += 1.0; SZ += z; SZ2 += z * z;
            } else {
                SP += (double)p; SP2 += (double)p * (double)p;
            }
        }
        double loss = A * SP2 + 2.0 * SZ * SP + SZ2 * ((double)n - A);
        out[0] = (float)loss;
    }
}

extern "C" void kernel_launch(void* const* d_in, const int* in_sizes, int n_in,
                              void* d_out, int out_size, void* d_ws, size_t ws_size,
                              hipStream_t stream)
{
    const float* pred = (const float*)d_in[0];
    const int*   lab  = (const int*)d_in[1];
    float*       out  = (float*)d_out;
    float*       ws   = (float*)d_ws;

    int n    = in_sizes[0];
    int nvec = n >> 2;                        // float4 / int4 groups
    int tail = nvec << 2;

    // one private slot per block; plain stores -> no memset needed
    int blocks = MAX_BLOCKS;
    int needed = (nvec + BLOCK * 2 - 1) / (BLOCK * 2);
    if (blocks > needed) blocks = needed;
    size_t max_slots = ws_size / (SLOT_STRIDE * sizeof(float));
    if (max_slots > 0 && (size_t)blocks > max_slots) blocks = (int)max_slots;
    if (blocks < 1) blocks = 1;

    hinge2_reduce<<<blocks, BLOCK, 0, stream>>>(pred, lab, ws, nvec);
    hinge2_final<<<1, BLOCK, 0, stream>>>(ws, pred, lab, out, n, tail, blocks);
}

// Round 3
// 265.693 us; speedup vs baseline: 1.0431x; 1.0406x over previous
//
#include <hip/hip_runtime.h>

// loss = a*sum(pn^2) + 2*sum(z)*sum(pn) + sum(z^2)*(N - a)
//   z = (margin - p) on positives, pn = p on negatives, a = #positives.
// Streaming reduction: 268 MB read, one scalar out.
//
// R7 theory: R5 (deep ILP, 16% occ) and R6 (TLP-max, 62% occ) both pinned at
// exactly ~100 us, VALUBusy 8.7%, FETCH 134 MB (= half the input), 1.33 TB/s
// HBM -> NOT latency-bound; throughput-capped at 2.7 TB/s effective. Working
// set (256 MiB) == L3 capacity: thrash regime, half hits / half misses, both
// paths far below their ceilings. Kernel-side lever = cache policy:
//   - labels: __builtin_nontemporal_load (nt bit) -> never allocate L3,
//     stream pure HBM.
//   - predictions: normal loads -> 128 MB fits ALONE in 256 MB L3, should
//     become ~fully resident across bench iterations.
// Predict: FETCH ~134 MB (labels only) + dur 100 -> 30-60 us if retention
// works; FETCH ~262 MB if not (then dur tells us the pure-HBM rate).
// Everything else identical to R6 (VGPR 24, 2048 blocks, 32 waves/CU).

constexpr float MARGIN = 1.0f;

#define BLOCK 256
#define MAX_BLOCKS 2048
#define SLOT_STRIDE 8            // floats per block slot (32 B)

typedef float v4f __attribute__((ext_vector_type(4)));
typedef int   v4i __attribute__((ext_vector_type(4)));

__device__ __forceinline__ float wave_reduce(float v) {
    #pragma unroll
    for (int off = 32; off > 0; off >>= 1) v += __shfl_down(v, off, 64);
    return v;
}

struct Acc { float a, sz, sz2, sp, sp2; };

__device__ __forceinline__ void acc1(float px, int lx, Acc& s) {
    float ispos = (lx == 1) ? 1.0f : 0.0f;
    float z  = ispos * (MARGIN - px);
    s.a   += ispos;
    s.sz  += z;
    s.sz2  = fmaf(z, z, s.sz2);
    float pn = (lx == 1) ? 0.0f : px;
    s.sp  += pn;
    s.sp2  = fmaf(pn, pn, s.sp2);
}

__device__ __forceinline__ void acc4(const v4f& p, const v4i& l, Acc& s) {
    acc1(p[0], l[0], s);
    acc1(p[1], l[1], s);
    acc1(p[2], l[2], s);
    acc1(p[3], l[3], s);
}

__global__ __launch_bounds__(BLOCK, 8) void hinge2_reduce(
    const float* __restrict__ pred, const int* __restrict__ lab,
    float* __restrict__ ws, int nvec)
{
    const v4f* p4 = reinterpret_cast<const v4f*>(pred);
    const v4i* l4 = reinterpret_cast<const v4i*>(lab);

    Acc s = {0.f, 0.f, 0.f, 0.f, 0.f};
    const int tid  = threadIdx.x;
    const int step = gridDim.x * (BLOCK * 2);
    int i = blockIdx.x * (BLOCK * 2) + tid;

    // main grid-stride loop: 2 float4-groups per thread per iteration
    // pred: normal load (L3-allocating, should pin resident at 128 MB)
    // lab:  non-temporal (nt bit -> no L3 allocation, pure HBM stream)
    while (i + BLOCK < nvec) {
        v4f p0 = p4[i];
        v4f p1 = p4[i + BLOCK];
        v4i l0 = __builtin_nontemporal_load(l4 + i);
        v4i l1 = __builtin_nontemporal_load(l4 + i + BLOCK);
        acc4(p0, l0, s);
        acc4(p1, l1, s);
        i += step;
    }
    if (i < nvec) {                       // odd trailing group
        v4f p = p4[i];
        v4i l = __builtin_nontemporal_load(l4 + i);
        acc4(p, l, s);
    }

    // block reduction
    s.a   = wave_reduce(s.a);
    s.sz  = wave_reduce(s.sz);
    s.sz2 = wave_reduce(s.sz2);
    s.sp  = wave_reduce(s.sp);
    s.sp2 = wave_reduce(s.sp2);

    __shared__ float sdata[4][5];
    int lane = tid & 63;
    int wid  = tid >> 6;
    if (lane == 0) {
        sdata[wid][0] = s.a;
        sdata[wid][1] = s.sz;
        sdata[wid][2] = s.sz2;
        sdata[wid][3] = s.sp;
        sdata[wid][4] = s.sp2;
    }
    __syncthreads();

    if (tid == 0) {
        float t0 = 0.f, t1 = 0.f, t2 = 0.f, t3 = 0.f, t4 = 0.f;
        #pragma unroll
        for (int w = 0; w < 4; ++w) {
            t0 += sdata[w][0];
            t1 += sdata[w][1];
            t2 += sdata[w][2];
            t3 += sdata[w][3];
            t4 += sdata[w][4];
        }
        float* slot = ws + (size_t)blockIdx.x * SLOT_STRIDE;
        slot[0] = t0;  // plain stores to a private slot: no init required
        slot[1] = t1;
        slot[2] = t2;
        slot[3] = t3;
        slot[4] = t4;
    }
}

__global__ __launch_bounds__(BLOCK) void hinge2_final(
    const float* __restrict__ ws,
    const float* __restrict__ pred, const int* __restrict__ lab,
    float* __restrict__ out, int n, int tail_start, int nslots)
{
    int t = threadIdx.x;
    double a = 0., sz = 0., sz2 = 0., sp = 0., sp2 = 0.;
    for (int b = t; b < nslots; b += BLOCK) {
        const float* slot = ws + (size_t)b * SLOT_STRIDE;
        a   += (double)slot[0];
        sz  += (double)slot[1];
        sz2 += (double)slot[2];
        sp  += (double)slot[3];
        sp2 += (double)slot[4];
    }
    #pragma unroll
    for (int off = 32; off > 0; off >>= 1) {
        a   += __shfl_down(a,   off, 64);
        sz  += __shfl_down(sz,  off, 64);
        sz2 += __shfl_down(sz2, off, 64);
        sp  += __shfl_down(sp,  off, 64);
        sp2 += __shfl_down(sp2, off, 64);
    }

    __shared__ double sdata[4][5];
    int lane = t & 63, wid = t >> 6;
    if (lane == 0) {
        sdata[wid][0] = a;  sdata[wid][1] = sz; sdata[wid][2] = sz2;
        sdata[wid][3] = sp; sdata[wid][4] = sp2;
    }
    __syncthreads();

    if (t == 0) {
        double A = 0, SZ = 0, SZ2 = 0, SP = 0, SP2 = 0;
        #pragma unroll
        for (int w = 0; w < 4; ++w) {
            A   += sdata[w][0];
            SZ  += sdata[w][1];
            SZ2 += sdata[w][2];
            SP  += sdata[w][3];
            SP2 += sdata[w][4];
        }
        for (int i = tail_start; i < n; ++i) {
            float p = pred[i];
            if (lab[i] == 1) {
                double z = (double)MARGIN - (double)p;
                A += 1.0; SZ += z; SZ2 += z * z;
            } else {
                SP += (double)p; SP2 += (double)p * (double)p;
            }
        }
        double loss = A * SP2 + 2.0 * SZ * SP + SZ2 * ((double)n - A);
        out[0] = (float)loss;
    }
}

extern "C" void kernel_launch(void* const* d_in, const int* in_sizes, int n_in,
                              void* d_out, int out_size, void* d_ws, size_t ws_size,
                              hipStream_t stream)
{
    const float* pred = (const float*)d_in[0];
    const int*   lab  = (const int*)d_in[1];
    float*       out  = (float*)d_out;
    float*       ws   = (float*)d_ws;

    int n    = in_sizes[0];
    int nvec = n >> 2;                        // float4 / int4 groups
    int tail = nvec << 2;

    // one private slot per block; plain stores -> no memset needed
    int blocks = MAX_BLOCKS;
    int needed = (nvec + BLOCK * 2 - 1) / (BLOCK * 2);
    if (blocks > needed) blocks = needed;
    size_t max_slots = ws_size / (SLOT_STRIDE * sizeof(float));
    if (max_slots > 0 && (size_t)blocks > max_slots) blocks = (int)max_slots;
    if (blocks < 1) blocks = 1;

    hinge2_reduce<<<blocks, BLOCK, 0, stream>>>(pred, lab, ws, nvec);
    hinge2_final<<<1, BLOCK, 0, stream>>>(ws, pred, lab, out, n, tail, blocks);
}

// Round 4
// 250.605 us; speedup vs baseline: 1.1059x; 1.0602x over previous
//
#include <hip/hip_runtime.h>

// loss = a*sum(pn^2) + 2*sum(z)*sum(pn) + sum(z^2)*(N - a)
//   z = (margin - p) on positives, pn = p on negatives, a = #positives.
// Streaming reduction: 268 MB read, one scalar out.
//
// R8 theory: R7 (nt labels) cut reduce 100 -> 78.7 us; FETCH still 134 MB but
// now = labels only (pred fully L3-resident). The harness's 512 MiB ws poison
// fill runs at 6.8 TB/s pure-write -> fabric can stream ~2x our current rate.
// The L3-hit path (pred @ 1.7 TB/s) is the drag: mixed L3-hit/HBM-miss
// underperforms both pure paths. This version: nt on BOTH streams -> zero L3
// involvement, pure HBM read stream.
// Predict: FETCH ~262 MB; reduce 78.7 -> 42-55 us if pure-read matches the
// fill's 6.8 TB/s; if it stays ~78 us, HBM-read caps at 3.4 TB/s and R7 was
// already optimal (revert next round).

constexpr float MARGIN = 1.0f;

#define BLOCK 256
#define MAX_BLOCKS 2048
#define SLOT_STRIDE 8            // floats per block slot (32 B)

typedef float v4f __attribute__((ext_vector_type(4)));
typedef int   v4i __attribute__((ext_vector_type(4)));

__device__ __forceinline__ float wave_reduce(float v) {
    #pragma unroll
    for (int off = 32; off > 0; off >>= 1) v += __shfl_down(v, off, 64);
    return v;
}

struct Acc { float a, sz, sz2, sp, sp2; };

__device__ __forceinline__ void acc1(float px, int lx, Acc& s) {
    float ispos = (lx == 1) ? 1.0f : 0.0f;
    float z  = ispos * (MARGIN - px);
    s.a   += ispos;
    s.sz  += z;
    s.sz2  = fmaf(z, z, s.sz2);
    float pn = (lx == 1) ? 0.0f : px;
    s.sp  += pn;
    s.sp2  = fmaf(pn, pn, s.sp2);
}

__device__ __forceinline__ void acc4(const v4f& p, const v4i& l, Acc& s) {
    acc1(p[0], l[0], s);
    acc1(p[1], l[1], s);
    acc1(p[2], l[2], s);
    acc1(p[3], l[3], s);
}

__global__ __launch_bounds__(BLOCK, 8) void hinge2_reduce(
    const float* __restrict__ pred, const int* __restrict__ lab,
    float* __restrict__ ws, int nvec)
{
    const v4f* p4 = reinterpret_cast<const v4f*>(pred);
    const v4i* l4 = reinterpret_cast<const v4i*>(lab);

    Acc s = {0.f, 0.f, 0.f, 0.f, 0.f};
    const int tid  = threadIdx.x;
    const int step = gridDim.x * (BLOCK * 2);
    int i = blockIdx.x * (BLOCK * 2) + tid;

    // main grid-stride loop: 2 float4-groups per thread per iteration
    // BOTH streams non-temporal: no L3 allocation, pure HBM stream.
    while (i + BLOCK < nvec) {
        v4f p0 = __builtin_nontemporal_load(p4 + i);
        v4f p1 = __builtin_nontemporal_load(p4 + i + BLOCK);
        v4i l0 = __builtin_nontemporal_load(l4 + i);
        v4i l1 = __builtin_nontemporal_load(l4 + i + BLOCK);
        acc4(p0, l0, s);
        acc4(p1, l1, s);
        i += step;
    }
    if (i < nvec) {                       // odd trailing group
        v4f p = __builtin_nontemporal_load(p4 + i);
        v4i l = __builtin_nontemporal_load(l4 + i);
        acc4(p, l, s);
    }

    // block reduction
    s.a   = wave_reduce(s.a);
    s.sz  = wave_reduce(s.sz);
    s.sz2 = wave_reduce(s.sz2);
    s.sp  = wave_reduce(s.sp);
    s.sp2 = wave_reduce(s.sp2);

    __shared__ float sdata[4][5];
    int lane = tid & 63;
    int wid  = tid >> 6;
    if (lane == 0) {
        sdata[wid][0] = s.a;
        sdata[wid][1] = s.sz;
        sdata[wid][2] = s.sz2;
        sdata[wid][3] = s.sp;
        sdata[wid][4] = s.sp2;
    }
    __syncthreads();

    if (tid == 0) {
        float t0 = 0.f, t1 = 0.f, t2 = 0.f, t3 = 0.f, t4 = 0.f;
        #pragma unroll
        for (int w = 0; w < 4; ++w) {
            t0 += sdata[w][0];
            t1 += sdata[w][1];
            t2 += sdata[w][2];
            t3 += sdata[w][3];
            t4 += sdata[w][4];
        }
        float* slot = ws + (size_t)blockIdx.x * SLOT_STRIDE;
        slot[0] = t0;  // plain stores to a private slot: no init required
        slot[1] = t1;
        slot[2] = t2;
        slot[3] = t3;
        slot[4] = t4;
    }
}

__global__ __launch_bounds__(BLOCK) void hinge2_final(
    const float* __restrict__ ws,
    const float* __restrict__ pred, const int* __restrict__ lab,
    float* __restrict__ out, int n, int tail_start, int nslots)
{
    int t = threadIdx.x;
    double a = 0., sz = 0., sz2 = 0., sp = 0., sp2 = 0.;
    for (int b = t; b < nslots; b += BLOCK) {
        const float* slot = ws + (size_t)b * SLOT_STRIDE;
        a   += (double)slot[0];
        sz  += (double)slot[1];
        sz2 += (double)slot[2];
        sp  += (double)slot[3];
        sp2 += (double)slot[4];
    }
    #pragma unroll
    for (int off = 32; off > 0; off >>= 1) {
        a   += __shfl_down(a,   off, 64);
        sz  += __shfl_down(sz,  off, 64);
        sz2 += __shfl_down(sz2, off, 64);
        sp  += __shfl_down(sp,  off, 64);
        sp2 += __shfl_down(sp2, off, 64);
    }

    __shared__ double sdata[4][5];
    int lane = t & 63, wid = t >> 6;
    if (lane == 0) {
        sdata[wid][0] = a;  sdata[wid][1] = sz; sdata[wid][2] = sz2;
        sdata[wid][3] = sp; sdata[wid][4] = sp2;
    }
    __syncthreads();

    if (t == 0) {
        double A = 0, SZ = 0, SZ2 = 0, SP = 0, SP2 = 0;
        #pragma unroll
        for (int w = 0; w < 4; ++w) {
            A   += sdata[w][0];
            SZ  += sdata[w][1];
            SZ2 += sdata[w][2];
            SP  += sdata[w][3];
            SP2 += sdata[w][4];
        }
        for (int i = tail_start; i < n; ++i) {
            float p = pred[i];
            if (lab[i] == 1) {
                double z = (double)MARGIN - (double)p;
                A += 1.0; SZ += z; SZ2 += z * z;
            } else {
                SP += (double)p; SP2 += (double)p * (double)p;
            }
        }
        double loss = A * SP2 + 2.0 * SZ * SP + SZ2 * ((double)n - A);
        out[0] = (float)loss;
    }
}

extern "C" void kernel_launch(void* const* d_in, const int* in_sizes, int n_in,
                              void* d_out, int out_size, void* d_ws, size_t ws_size,
                              hipStream_t stream)
{
    const float* pred = (const float*)d_in[0];
    const int*   lab  = (const int*)d_in[1];
    float*       out  = (float*)d_out;
    float*       ws   = (float*)d_ws;

    int n    = in_sizes[0];
    int nvec = n >> 2;                        // float4 / int4 groups
    int tail = nvec << 2;

    // one private slot per block; plain stores -> no memset needed
    int blocks = MAX_BLOCKS;
    int needed = (nvec + BLOCK * 2 - 1) / (BLOCK * 2);
    if (blocks > needed) blocks = needed;
    size_t max_slots = ws_size / (SLOT_STRIDE * sizeof(float));
    if (max_slots > 0 && (size_t)blocks > max_slots) blocks = (int)max_slots;
    if (blocks < 1) blocks = 1;

    hinge2_reduce<<<blocks, BLOCK, 0, stream>>>(pred, lab, ws, nvec);
    hinge2_final<<<1, BLOCK, 0, stream>>>(ws, pred, lab, out, n, tail, blocks);
}